// Round 1
// baseline (2945.231 us; speedup 1.0000x reference)
//
#include <hip/hip_runtime.h>

#define BATCH 262144
// D = 128 fixed.

// ---------------- workspace layout ----------------
// [0, 131072)          Rt64 : double[128][128], Rt64[j*128+k] = R[k][j]  (i.e. R^T row-major)
// [131072, 196608)     R32  : float [128][128], row-major R[k][j]
// [196608, 1245184)    norm32 : float[BATCH]
// [1245184, 34799616)  idx  : u8[BATCH*128]

// =======================================================================
// K_pre: build M = I + A from skew params, Gauss-Jordan invert in LDS
// (cond(I+A) ~ 1.5, PD symmetric part -> no pivoting), then
// R = (I+A)^-1 (I-A) = 2*(I+A)^-1 - I.  Write R^T (f64) and R (f32).
// =======================================================================
__global__ __launch_bounds__(1024, 4)
void kpre_invert(const float* __restrict__ skew, double* __restrict__ Rt64,
                 float* __restrict__ R32)
{
  extern __shared__ char smem[];
  double* M    = (double*)smem;               // [128][128] = 131072 B
  double* colk = (double*)(smem + 131072);    // [128]
  const int tid = threadIdx.x;
  const int i   = tid >> 3;          // row 0..127
  const int c0  = (tid & 7) * 16;    // 16-col strip

  // build M = I + A  (A strict-upper params, antisymmetric)
  #pragma unroll
  for (int e = 0; e < 16; ++e) {
    int j = c0 + e;
    double v;
    if (i == j)      v = 1.0;
    else if (i < j)  v =  (double)skew[i*127 - (i*(i-1))/2 + (j - i - 1)];
    else             v = -(double)skew[j*127 - (j*(j-1))/2 + (i - j - 1)];
    M[i*128 + j] = v;
  }
  __syncthreads();

  for (int k = 0; k < 128; ++k) {
    double recip = 1.0 / M[k*128 + k];
    if (i == k) {
      #pragma unroll
      for (int e = 0; e < 16; ++e) {
        int j = c0 + e;
        double v = (j == k) ? 1.0 : M[k*128 + j];
        M[k*128 + j] = v * recip;
      }
    }
    __syncthreads();
    if (tid < 128) colk[tid] = M[tid*128 + k];   // stash pivot column once
    double mk[16];
    #pragma unroll
    for (int e = 0; e < 16; ++e) mk[e] = M[k*128 + c0 + e];
    __syncthreads();
    double f = colk[i];
    if (i != k) {
      #pragma unroll
      for (int e = 0; e < 16; ++e) {
        int j = c0 + e;
        double v = (j == k) ? 0.0 : M[i*128 + j];
        M[i*128 + j] = v - f * mk[e];
      }
    }
    __syncthreads();
  }

  // R[i][j] = 2*Minv[i][j] - delta_ij
  #pragma unroll
  for (int e = 0; e < 16; ++e) {
    int j = c0 + e;
    double v = 2.0 * M[i*128 + j] - ((i == j) ? 1.0 : 0.0);
    Rt64[j*128 + i] = v;          // R^T
    R32 [i*128 + j] = (float)v;   // R row-major
  }
}

// =======================================================================
// K1: f64 decision path. Per wave: 6 rows. x staged exact (f32->f64) in
// per-wave LDS; x_rot[k] = (sum_j x_j * Rt[j][k] - mrot[k]) / ||x - m||.
// Quantize by midpoint comparisons (== argmin|x-c|, ties to lower idx).
// =======================================================================
__global__ __launch_bounds__(256, 1)
void k1_rotquant(const float* __restrict__ x, const float* __restrict__ mean,
                 const float* __restrict__ cent, const double* __restrict__ Rt64g,
                 unsigned char* __restrict__ idxout, float* __restrict__ normout)
{
  extern __shared__ char smem[];
  double* RT    = (double*)smem;                       // [128][128] f64 = 131072 B
  double* XC    = (double*)(smem + 131072);            // [4][6][128] f64 = 24576 B
  double* NORMS = (double*)(smem + 131072 + 24576);    // [4][6][2] (norm, 1/norm)

  const int tid  = threadIdx.x;
  const int lane = tid & 63;
  const int w    = tid >> 6;

  // stage R^T (131072 B) once
  for (int it = 0; it < 32; ++it) {
    int off = (it*256 + tid) * 16;
    *(float4*)((char*)RT + off) = *(const float4*)((const char*)Rt64g + off);
  }
  __syncthreads();

  // per-lane mean chunk (cols 4*(lane&31)..+3), f64
  const int mc = (lane & 31) * 4;
  double mv0 = (double)mean[mc+0], mv1 = (double)mean[mc+1];
  double mv2 = (double)mean[mc+2], mv3 = (double)mean[mc+3];

  // midpoints of sorted centroids (f64)
  double c64[8];
  #pragma unroll
  for (int t = 0; t < 8; ++t) c64[t] = (double)cent[t];
  double mid0 = 0.5*(c64[0]+c64[1]), mid1 = 0.5*(c64[1]+c64[2]);
  double mid2 = 0.5*(c64[2]+c64[3]), mid3 = 0.5*(c64[3]+c64[4]);
  double mid4 = 0.5*(c64[4]+c64[5]), mid5 = 0.5*(c64[5]+c64[6]);
  double mid6 = 0.5*(c64[6]+c64[7]);

  // mrot[k] = sum_j mean_j * Rt[j][k] for k = 2*lane, 2*lane+1
  double mrot0 = 0.0, mrot1 = 0.0;
  for (int j4 = 0; j4 < 32; ++j4) {
    double m0 = __shfl(mv0, j4), m1 = __shfl(mv1, j4);
    double m2 = __shfl(mv2, j4), m3 = __shfl(mv3, j4);
    double2 r0 = *(double2*)(RT + (4*j4+0)*128 + 2*lane);
    double2 r1 = *(double2*)(RT + (4*j4+1)*128 + 2*lane);
    double2 r2 = *(double2*)(RT + (4*j4+2)*128 + 2*lane);
    double2 r3 = *(double2*)(RT + (4*j4+3)*128 + 2*lane);
    mrot0 = fma(m0, r0.x, mrot0); mrot1 = fma(m0, r0.y, mrot1);
    mrot0 = fma(m1, r1.x, mrot0); mrot1 = fma(m1, r1.y, mrot1);
    mrot0 = fma(m2, r2.x, mrot0); mrot1 = fma(m2, r2.y, mrot1);
    mrot0 = fma(m3, r3.x, mrot0); mrot1 = fma(m3, r3.y, mrot1);
  }

  double* xcw = XC + w * (6*128);
  double* nw  = NORMS + w * 12;
  const int NG = (BATCH + 23) / 24;   // 24 rows per block-iter (4 waves x 6)

  for (int g = blockIdx.x; g < NG; g += gridDim.x) {
    const int rowbase = g*24 + w*6;

    // ---- stage 6 rows: exact f32 -> f64, compute norms ----
    #pragma unroll
    for (int rr = 0; rr < 3; ++rr) {
      int  r2  = rr*2 + (lane >> 5);
      long row = (long)rowbase + r2;
      float4 xv = make_float4(0.f, 0.f, 0.f, 0.f);
      if (row < BATCH)
        xv = *(const float4*)(x + (long)(rowbase + rr*2)*128 + lane*4);
      double a0 = (double)xv.x - mv0, a1 = (double)xv.y - mv1;
      double a2 = (double)xv.z - mv2, a3 = (double)xv.w - mv3;
      double s = a0*a0 + a1*a1 + a2*a2 + a3*a3;
      s += __shfl_xor(s, 1);  s += __shfl_xor(s, 2);  s += __shfl_xor(s, 4);
      s += __shfl_xor(s, 8);  s += __shfl_xor(s, 16);          // per 32-lane half
      double* dst = xcw + r2*128 + (lane & 31)*4;
      dst[0] = a0; dst[1] = a1; dst[2] = a2; dst[3] = a3;
      if ((lane & 31) == 0) {
        double nrm = sqrt(s);
        if (nrm < 1e-8) nrm = 1e-8;
        nw[r2*2 + 0] = nrm;
        nw[r2*2 + 1] = 1.0 / nrm;
      }
    }
    __syncthreads();   // lgkmcnt drain + keeps waves' LDS phases ordered

    // ---- mm1: acc[k] = sum_j xc_j * Rt[j][k], k = 2*lane, 2*lane+1 ----
    double acc0[6] = {0,0,0,0,0,0};
    double acc1[6] = {0,0,0,0,0,0};
    #pragma unroll 4
    for (int j = 0; j < 128; ++j) {
      double2 rt = *(double2*)(RT + j*128 + 2*lane);
      #pragma unroll
      for (int r = 0; r < 6; ++r) {
        double xj = xcw[r*128 + j];                 // broadcast read
        acc0[r] = fma(xj, rt.x, acc0[r]);
        acc1[r] = fma(xj, rt.y, acc1[r]);
      }
    }

    // ---- quantize + emit ----
    #pragma unroll
    for (int r = 0; r < 6; ++r) {
      long row = (long)rowbase + r;
      if (row < BATCH) {
        double rcp = nw[r*2 + 1];
        double xr0 = (acc0[r] - mrot0) * rcp;
        double xr1 = (acc1[r] - mrot1) * rcp;
        int i0 = (xr0 > mid0) + (xr0 > mid1) + (xr0 > mid2) + (xr0 > mid3)
               + (xr0 > mid4) + (xr0 > mid5) + (xr0 > mid6);
        int i1 = (xr1 > mid0) + (xr1 > mid1) + (xr1 > mid2) + (xr1 > mid3)
               + (xr1 > mid4) + (xr1 > mid5) + (xr1 > mid6);
        *(unsigned short*)(idxout + row*128 + 2*lane) =
            (unsigned short)(i0 | (i1 << 8));
        if (lane == 0) normout[row] = (float)nw[r*2];
      }
    }
    __syncthreads();
  }
}

// =======================================================================
// K2: out[r][j] = (sum_k c[idx[r][k]] * R[k][j]) * norm_r + mean_j   (f32)
// R resident in LDS; q broadcast across lanes via shfl.
// =======================================================================
__device__ __forceinline__ float csel(int idx, float t0, float t1, float t2,
                                      float t3, float t4, float t5, float t6,
                                      float t7)
{
  float a = (idx & 1) ? t1 : t0;
  float b = (idx & 1) ? t3 : t2;
  float c = (idx & 1) ? t5 : t4;
  float d = (idx & 1) ? t7 : t6;
  float e = (idx & 2) ? b : a;
  float f = (idx & 2) ? d : c;
  return (idx & 4) ? f : e;
}

__global__ __launch_bounds__(256, 2)
void k2_recon(const unsigned char* __restrict__ idxin,
              const float* __restrict__ normin,
              const float* __restrict__ R32g,
              const float* __restrict__ mean,
              const float* __restrict__ cent,
              float* __restrict__ out)
{
  extern __shared__ char smem[];
  float* R = (float*)smem;  // [128][128] f32 = 65536 B
  const int tid  = threadIdx.x;
  const int lane = tid & 63;
  const int w    = tid >> 6;

  for (int it = 0; it < 16; ++it) {
    int off = (it*256 + tid) * 16;
    *(float4*)((char*)R + off) = *(const float4*)((const char*)R32g + off);
  }
  __syncthreads();

  float t0 = cent[0], t1 = cent[1], t2 = cent[2], t3 = cent[3];
  float t4 = cent[4], t5 = cent[5], t6 = cent[6], t7 = cent[7];
  float me0 = mean[2*lane], me1 = mean[2*lane + 1];

  const int NCH = BATCH / 64;  // 64 rows per block-iter (4 waves x 16)
  for (int ch = blockIdx.x; ch < NCH; ch += gridDim.x) {
    const int rowbase = ch*64 + w*16;

    float q0[16], q1[16], nr[16];
    #pragma unroll
    for (int r = 0; r < 16; ++r) {
      long row = rowbase + r;
      unsigned short pk = *(const unsigned short*)(idxin + row*128 + 2*lane);
      q0[r] = csel(pk & 7,        t0,t1,t2,t3,t4,t5,t6,t7);
      q1[r] = csel((pk >> 8) & 7, t0,t1,t2,t3,t4,t5,t6,t7);
      nr[r] = normin[row];
    }

    float acc0[16];
    float acc1[16];
    #pragma unroll
    for (int r = 0; r < 16; ++r) { acc0[r] = 0.f; acc1[r] = 0.f; }

    for (int t = 0; t < 64; ++t) {
      float2 ra = *(float2*)(R + (2*t    )*128 + 2*lane);
      float2 rb = *(float2*)(R + (2*t + 1)*128 + 2*lane);
      #pragma unroll
      for (int r = 0; r < 16; ++r) {
        float qa = __shfl(q0[r], t);   // q for k = 2t
        float qb = __shfl(q1[r], t);   // q for k = 2t+1
        acc0[r] = fmaf(qa, ra.x, acc0[r]);
        acc1[r] = fmaf(qa, ra.y, acc1[r]);
        acc0[r] = fmaf(qb, rb.x, acc0[r]);
        acc1[r] = fmaf(qb, rb.y, acc1[r]);
      }
    }

    #pragma unroll
    for (int r = 0; r < 16; ++r) {
      long row = rowbase + r;
      float2 o;
      o.x = fmaf(acc0[r], nr[r], me0);
      o.y = fmaf(acc1[r], nr[r], me1);
      *(float2*)(out + row*128 + 2*lane) = o;
    }
  }
}

// =======================================================================
extern "C" void kernel_launch(void* const* d_in, const int* in_sizes, int n_in,
                              void* d_out, int out_size, void* d_ws, size_t ws_size,
                              hipStream_t stream)
{
  (void)in_sizes; (void)n_in; (void)out_size; (void)ws_size;
  const float* x    = (const float*)d_in[0];
  const float* skew = (const float*)d_in[1];
  const float* cent = (const float*)d_in[2];
  const float* mean = (const float*)d_in[3];
  float* out = (float*)d_out;

  char* ws = (char*)d_ws;
  double*        Rt64   = (double*)(ws);
  float*         R32    = (float*)(ws + 131072);
  float*         norm32 = (float*)(ws + 196608);
  unsigned char* idxb   = (unsigned char*)(ws + 1245184);

  kpre_invert<<<dim3(1),   dim3(1024), 131072 + 1024,          stream>>>(skew, Rt64, R32);
  k1_rotquant<<<dim3(256), dim3(256),  131072 + 24576 + 384,   stream>>>(x, mean, cent, Rt64, idxb, norm32);
  k2_recon   <<<dim3(512), dim3(256),  65536,                  stream>>>(idxb, norm32, R32, mean, cent, out);
}

// Round 2
// 650.966 us; speedup vs baseline: 4.5244x; 4.5244x over previous
//
#include <hip/hip_runtime.h>

#define BATCH 262144
#define MARGIN 4e-6f
#define LIST_CAP (2u*1024u*1024u)

// ---------------- workspace layout (bytes) ----------------
// 0        : Rt64  f64 [128][128]   Rt64[j*128+k] = R[k][j]        (131072)
// 131072   : RT32  f32 [128][128]   RT32[j*128+k] = R[k][j]        ( 65536)
// 196608   : R32   f32 [128][128]   R32 [k*128+j] = R[k][j]        ( 65536)
// 262144   : counter u32
// 262208   : norm32 f32 [BATCH]                                    (1048576)
// 1310784  : idxb  u8  [BATCH*64]  packed nibbles (lo=even k)      (16777216)
// 18088000 : list  u32 [LIST_CAP]                                  (8388608)  -> ends 26476608

// =======================================================================
// K_pre: register-resident Gauss-Jordan inversion of M = I + A.
// Thread tid: row i = tid>>3, s = tid&7, owns elements j = s + 8e (e<16).
// Only pivot column (colk) and scaled pivot row (pivrow) go through LDS;
// all LDS patterns are distinct-bank or same-address broadcast.
// R = (I+A)^-1 (I-A) = 2*(I+A)^-1 - I.
// =======================================================================
__global__ __launch_bounds__(1024)
void kpre_invert(const float* __restrict__ skew, double* __restrict__ Rt64,
                 float* __restrict__ RT32, float* __restrict__ R32)
{
  __shared__ double colk[128];
  __shared__ double pivrow[128];
  const int tid = threadIdx.x;
  const int i = tid >> 3;
  const int s = tid & 7;

  double M[16];
  #pragma unroll
  for (int e = 0; e < 16; ++e) {
    int j = s + 8*e;
    double v;
    if (i == j)      v = 1.0;
    else if (i < j)  v =  (double)skew[i*127 - (i*(i-1))/2 + (j - i - 1)];
    else             v = -(double)skew[j*127 - (j*(j-1))/2 + (i - j - 1)];
    M[e] = v;
  }
  __syncthreads();

  for (int k = 0; k < 128; ++k) {
    // A: owners of column k publish it
    if (s == (k & 7)) colk[i] = M[k >> 3];
    __syncthreads();
    // B: pivot row scales itself and publishes
    if (i == k) {
      double rec = 1.0 / colk[k];
      #pragma unroll
      for (int e = 0; e < 16; ++e) {
        int j = s + 8*e;
        double v = (j == k) ? 1.0 : M[e];
        v *= rec;
        M[e] = v;
        pivrow[j] = v;
      }
    }
    __syncthreads();
    // C: eliminate
    if (i != k) {
      double f = colk[i];
      #pragma unroll
      for (int e = 0; e < 16; ++e) {
        int j = s + 8*e;
        double v = (j == k) ? 0.0 : M[e];
        M[e] = fma(-f, pivrow[j], v);
      }
    }
    __syncthreads();
  }

  #pragma unroll
  for (int e = 0; e < 16; ++e) {
    int j = s + 8*e;
    double v = 2.0 * M[e] - ((i == j) ? 1.0 : 0.0);   // R[i][j]
    Rt64[j*128 + i] = v;
    RT32[j*128 + i] = (float)v;
    R32 [i*128 + j] = (float)v;
  }
}

__device__ __forceinline__ float rdlane(float v, int l) {
  return __int_as_float(__builtin_amdgcn_readlane(__float_as_int(v), l));
}

// =======================================================================
// K1: f32 fast path. Lane l owns output cols k=2l,2l+1 (RT col-pair from
// LDS) and input cols 2l,2l+1 of its wave's 8 rows (registers); x values
// broadcast across the wave via v_readlane (VALU pipe, no LDS traffic).
// Elements within MARGIN of a quantization midpoint are appended to a
// patch list for exact f64 recompute in k1b.
// =======================================================================
__global__ __launch_bounds__(256, 2)
void k1_rotquant(const float* __restrict__ x, const float* __restrict__ mean,
                 const float* __restrict__ cent, const float* __restrict__ RT32g,
                 unsigned char* __restrict__ idxb, float* __restrict__ normout,
                 unsigned int* __restrict__ counter, unsigned int* __restrict__ list)
{
  __shared__ float RT[128*128];   // 64 KB, RT[j*128+k]
  const int tid  = threadIdx.x;
  const int lane = tid & 63;
  const int w    = tid >> 6;

  for (int it = 0; it < 16; ++it) {
    int off = (it*256 + tid) * 4;
    *(float4*)(RT + off) = *(const float4*)(RT32g + off);
  }
  __syncthreads();

  const float2 mv = *(const float2*)(mean + 2*lane);
  float c[8];
  #pragma unroll
  for (int t = 0; t < 8; ++t) c[t] = cent[t];
  float mid[7];
  #pragma unroll
  for (int t = 0; t < 7; ++t) mid[t] = 0.5f*(c[t] + c[t+1]);

  // mrot[k] = sum_j mean_j * R[k][j] for k = 2*lane, 2*lane+1
  float mrot0 = 0.f, mrot1 = 0.f;
  for (int j2 = 0; j2 < 64; ++j2) {
    float sa = rdlane(mv.x, j2);
    float sb = rdlane(mv.y, j2);
    float2 re = *(float2*)(RT + (2*j2    )*128 + 2*lane);
    float2 ro = *(float2*)(RT + (2*j2 + 1)*128 + 2*lane);
    mrot0 = fmaf(sa, re.x, fmaf(sb, ro.x, mrot0));
    mrot1 = fmaf(sa, re.y, fmaf(sb, ro.y, mrot1));
  }

  const int rowbase0 = blockIdx.x * 512;
  for (int ch = 0; ch < 16; ++ch) {
    const int rowbase = rowbase0 + ch*32 + w*8;

    float xa[8], xb[8], nrmv[8], inv[8];
    #pragma unroll
    for (int r = 0; r < 8; ++r) {
      float2 xv = *(const float2*)(x + (size_t)(rowbase + r)*128 + 2*lane);
      xa[r] = xv.x - mv.x;
      xb[r] = xv.y - mv.y;
      float sq = fmaf(xa[r], xa[r], xb[r]*xb[r]);
      sq += __shfl_xor(sq, 1);  sq += __shfl_xor(sq, 2);  sq += __shfl_xor(sq, 4);
      sq += __shfl_xor(sq, 8);  sq += __shfl_xor(sq, 16); sq += __shfl_xor(sq, 32);
      float n = fmaxf(sqrtf(sq), 1e-8f);
      nrmv[r] = n;
      inv[r]  = 1.0f / n;
    }

    float acc0[8], acc1[8];
    #pragma unroll
    for (int r = 0; r < 8; ++r) { acc0[r] = 0.f; acc1[r] = 0.f; }

    #pragma unroll 4
    for (int j2 = 0; j2 < 64; ++j2) {
      float2 re = *(float2*)(RT + (2*j2    )*128 + 2*lane);
      float2 ro = *(float2*)(RT + (2*j2 + 1)*128 + 2*lane);
      #pragma unroll
      for (int r = 0; r < 8; ++r) {
        float sa = rdlane(xa[r], j2);
        float sb = rdlane(xb[r], j2);
        acc0[r] = fmaf(sa, re.x, acc0[r]);
        acc0[r] = fmaf(sb, ro.x, acc0[r]);
        acc1[r] = fmaf(sa, re.y, acc1[r]);
        acc1[r] = fmaf(sb, ro.y, acc1[r]);
      }
    }

    #pragma unroll
    for (int r = 0; r < 8; ++r) {
      const int row = rowbase + r;
      float xr0 = (acc0[r] - mrot0) * inv[r];
      float xr1 = (acc1[r] - mrot1) * inv[r];
      int i0 = 0, i1 = 0;
      float d0 = 1e30f, d1 = 1e30f;
      #pragma unroll
      for (int t = 0; t < 7; ++t) {
        i0 += (xr0 > mid[t]);  d0 = fminf(d0, fabsf(xr0 - mid[t]));
        i1 += (xr1 > mid[t]);  d1 = fminf(d1, fabsf(xr1 - mid[t]));
      }
      idxb[(size_t)row*64 + lane] = (unsigned char)(i0 | (i1 << 4));
      if (lane == 0) normout[row] = nrmv[r];

      unsigned long long b0 = __ballot(d0 < MARGIN);
      unsigned long long b1 = __ballot(d1 < MARGIN);
      if (b0 | b1) {
        int tot = __popcll(b0) + __popcll(b1);
        unsigned int base = 0;
        if (lane == 0) base = atomicAdd(counter, (unsigned int)tot);
        base = __shfl(base, 0);
        unsigned long long lm = (1ull << lane) - 1ull;
        if (d0 < MARGIN) {
          unsigned int p = base + (unsigned)__popcll(b0 & lm);
          if (p < LIST_CAP) list[p] = (unsigned)(row*128 + 2*lane);
        }
        if (d1 < MARGIN) {
          unsigned int p = base + (unsigned)__popcll(b0) + (unsigned)__popcll(b1 & lm);
          if (p < LIST_CAP) list[p] = (unsigned)(row*128 + 2*lane + 1);
        }
      }
    }
  }
}

// =======================================================================
// K1b: exact f64 recompute of flagged elements; CAS-patch packed nibble.
// =======================================================================
__global__ __launch_bounds__(256)
void k1b_patch(const float* __restrict__ x, const float* __restrict__ mean,
               const float* __restrict__ cent, const double* __restrict__ Rt64,
               unsigned char* __restrict__ idxb,
               const unsigned int* __restrict__ counter,
               const unsigned int* __restrict__ list)
{
  unsigned int cnt = *counter;
  if (cnt > LIST_CAP) cnt = LIST_CAP;
  double mid[7];
  #pragma unroll
  for (int t = 0; t < 7; ++t) mid[t] = 0.5*((double)cent[t] + (double)cent[t+1]);

  const unsigned int gsz = gridDim.x * blockDim.x;
  for (unsigned int e = blockIdx.x*blockDim.x + threadIdx.x; e < cnt; e += gsz) {
    unsigned int v = list[e];
    int row = (int)(v >> 7), k = (int)(v & 127);
    const float* xr = x + (size_t)row*128;

    double s = 0.0;
    for (int j = 0; j < 128; ++j) {
      double d = (double)xr[j] - (double)mean[j];
      s = fma(d, d, s);
    }
    double n = sqrt(s);
    if (n < 1e-8) n = 1e-8;
    double invn = 1.0 / n;
    double dot = 0.0;
    for (int j = 0; j < 128; ++j) {
      double u = ((double)xr[j] - (double)mean[j]) * invn;
      dot = fma(u, Rt64[j*128 + k], dot);
    }
    int idx = 0;
    #pragma unroll
    for (int t = 0; t < 7; ++t) idx += (dot > mid[t]);

    unsigned int byteoff = (unsigned)(row*64 + (k >> 1));
    unsigned int wordoff = byteoff >> 2;
    int shift = (int)(byteoff & 3)*8 + (k & 1)*4;
    unsigned int maskbits = 0xFu << shift;
    unsigned int* wp = (unsigned int*)idxb + wordoff;
    unsigned int oldv = *wp, assumed;
    do {
      assumed = oldv;
      unsigned int newv = (assumed & ~maskbits) | (((unsigned)idx) << shift);
      oldv = atomicCAS(wp, assumed, newv);
    } while (oldv != assumed);
  }
}

// =======================================================================
// K2: out[row][j] = (sum_k c[idx[row][k]] * R[k][j]) * norm + mean[j]
// Lane l owns j = 2l,2l+1; q values broadcast via v_readlane.
// =======================================================================
__device__ __forceinline__ float csel8(int idx, float t0, float t1, float t2,
                                       float t3, float t4, float t5, float t6,
                                       float t7)
{
  float a = (idx & 1) ? t1 : t0;
  float b = (idx & 1) ? t3 : t2;
  float cc = (idx & 1) ? t5 : t4;
  float d = (idx & 1) ? t7 : t6;
  float e = (idx & 2) ? b : a;
  float f = (idx & 2) ? d : cc;
  return (idx & 4) ? f : e;
}

__global__ __launch_bounds__(256, 2)
void k2_recon(const unsigned char* __restrict__ idxb,
              const float* __restrict__ normin,
              const float* __restrict__ R32g,
              const float* __restrict__ mean,
              const float* __restrict__ cent,
              float* __restrict__ out)
{
  __shared__ float R[128*128];   // 64 KB, R[k*128+j]
  const int tid  = threadIdx.x;
  const int lane = tid & 63;
  const int w    = tid >> 6;

  for (int it = 0; it < 16; ++it) {
    int off = (it*256 + tid) * 4;
    *(float4*)(R + off) = *(const float4*)(R32g + off);
  }
  __syncthreads();

  float t0 = cent[0], t1 = cent[1], t2 = cent[2], t3 = cent[3];
  float t4 = cent[4], t5 = cent[5], t6 = cent[6], t7 = cent[7];
  const float2 mv = *(const float2*)(mean + 2*lane);

  const int rowbase0 = blockIdx.x * 512;
  for (int ch = 0; ch < 16; ++ch) {
    const int rowbase = rowbase0 + ch*32 + w*8;

    float q0[8], q1[8], nr[8];
    #pragma unroll
    for (int r = 0; r < 8; ++r) {
      unsigned int b = idxb[(size_t)(rowbase + r)*64 + lane];
      q0[r] = csel8((int)(b & 7), t0,t1,t2,t3,t4,t5,t6,t7);
      q1[r] = csel8((int)((b >> 4) & 7), t0,t1,t2,t3,t4,t5,t6,t7);
      nr[r] = normin[rowbase + r];
    }

    float acc0[8], acc1[8];
    #pragma unroll
    for (int r = 0; r < 8; ++r) { acc0[r] = 0.f; acc1[r] = 0.f; }

    #pragma unroll 4
    for (int kk = 0; kk < 64; ++kk) {
      float2 re = *(float2*)(R + (2*kk    )*128 + 2*lane);
      float2 ro = *(float2*)(R + (2*kk + 1)*128 + 2*lane);
      #pragma unroll
      for (int r = 0; r < 8; ++r) {
        float qa = rdlane(q0[r], kk);
        float qb = rdlane(q1[r], kk);
        acc0[r] = fmaf(qa, re.x, acc0[r]);
        acc0[r] = fmaf(qb, ro.x, acc0[r]);
        acc1[r] = fmaf(qa, re.y, acc1[r]);
        acc1[r] = fmaf(qb, ro.y, acc1[r]);
      }
    }

    #pragma unroll
    for (int r = 0; r < 8; ++r) {
      float2 o;
      o.x = fmaf(acc0[r], nr[r], mv.x);
      o.y = fmaf(acc1[r], nr[r], mv.y);
      *(float2*)(out + (size_t)(rowbase + r)*128 + 2*lane) = o;
    }
  }
}

// =======================================================================
extern "C" void kernel_launch(void* const* d_in, const int* in_sizes, int n_in,
                              void* d_out, int out_size, void* d_ws, size_t ws_size,
                              hipStream_t stream)
{
  (void)in_sizes; (void)n_in; (void)out_size; (void)ws_size;
  const float* x    = (const float*)d_in[0];
  const float* skew = (const float*)d_in[1];
  const float* cent = (const float*)d_in[2];
  const float* mean = (const float*)d_in[3];
  float* out = (float*)d_out;

  char* ws = (char*)d_ws;
  double*        Rt64   = (double*)(ws);
  float*         RT32   = (float*)(ws + 131072);
  float*         R32    = (float*)(ws + 196608);
  unsigned int*  cntr   = (unsigned int*)(ws + 262144);
  float*         norm32 = (float*)(ws + 262208);
  unsigned char* idxb   = (unsigned char*)(ws + 1310784);
  unsigned int*  list   = (unsigned int*)(ws + 18088000);

  hipMemsetAsync(cntr, 0, 4, stream);
  kpre_invert<<<dim3(1),   dim3(1024), 0, stream>>>(skew, Rt64, RT32, R32);
  k1_rotquant<<<dim3(512), dim3(256),  0, stream>>>(x, mean, cent, RT32, idxb, norm32, cntr, list);
  k1b_patch  <<<dim3(128), dim3(256),  0, stream>>>(x, mean, cent, Rt64, idxb, cntr, list);
  k2_recon   <<<dim3(512), dim3(256),  0, stream>>>(idxb, norm32, R32, mean, cent, out);
}